// Round 1
// baseline (131.493 us; speedup 1.0000x reference)
//
#include <hip/hip_runtime.h>
#include <stdint.h>

#define NPTS 4096
#define NC 128
#define NB 8
#define CSPLIT 8
#define COLS_PER (NPTS / CSPLIT)  // 512
#define RPB 128                   // rows per block (4 waves x 32 rows)

typedef __bf16 bf16x8 __attribute__((ext_vector_type(8)));
typedef float f32x4 __attribute__((ext_vector_type(4)));
typedef unsigned short u16;
typedef unsigned int u32;
typedef unsigned long long u64;

__device__ inline float fast_exp2(float x) { return __builtin_amdgcn_exp2f(x); }

__device__ inline u16 f2bf(float x) {
    u32 u = __float_as_uint(x);
    u32 r = (u + 0x7fffu + ((u >> 16) & 1u)) >> 16;
    return (u16)r;
}

// direct global->LDS DMA, 16B per lane (dest = wave-uniform base + lane*16)
typedef __attribute__((address_space(1))) const void glb_void;
typedef __attribute__((address_space(3))) void lds_void;
__device__ inline void gload_lds16(const void* g, void* l) {
    __builtin_amdgcn_global_load_lds((glb_void*)g, (lds_void*)l, 16, 0, 0);
}

// Kernel 0: per-cloud label histogram, per-(chunk,label) scatter bases,
// totals for the loss denominators, zero acc/ticket.
__global__ __launch_bounds__(256) void hist_kernel(const int* __restrict__ labels,
                                                   int* __restrict__ counts,
                                                   int* __restrict__ baseg,
                                                   u32* __restrict__ zb) {
    int b = blockIdx.x, tid = threadIdx.x;
    if (b == 0 && tid < 2) zb[tid] = 0u;
    __shared__ int cnt[64][16];
    __shared__ int tot[16];
    for (int i = tid; i < 64 * 16; i += 256) ((int*)cnt)[i] = 0;
    __syncthreads();
    for (int n = tid; n < NPTS; n += 256)
        atomicAdd(&cnt[n >> 6][labels[b * NPTS + n] & 15], 1);
    __syncthreads();
    if (tid < 16) {
        int s = 0;
        for (int k = 0; k < 64; ++k) s += cnt[k][tid];
        counts[b * 16 + tid] = s;
        tot[tid] = s;
    }
    __syncthreads();
    if (tid == 0) {
        int run = 0;
        for (int l = 0; l < 16; ++l) { int c = tot[l]; tot[l] = run; run += c; }
    }
    __syncthreads();
    if (tid < 16) {  // exclusive scan over 64-point chunks per label
        int run = tot[tid];
        for (int k = 0; k < 64; ++k) {
            baseg[(b * 64 + k) * 16 + tid] = run;
            run += cnt[k][tid];
        }
    }
}

// Kernel 1: normalize + counting-sort scatter (deterministic: ballot ranks).
__global__ __launch_bounds__(256) void norm_kernel(const float* __restrict__ feat,
                                                   const int* __restrict__ labels,
                                                   const int* __restrict__ baseg,
                                                   u16* __restrict__ vbf,
                                                   int* __restrict__ slab) {
    int b = blockIdx.y;
    int blk = blockIdx.x;
    int tid = threadIdx.x;
    int n0 = blk * 64;
    __shared__ float tile[64][129];
    __shared__ float part[8][64];
    __shared__ float rn[64];
    __shared__ int lpos[64];
    const float* fb = feat + (size_t)b * NC * NPTS;
    int nslot = tid & 31;
    int ty = tid >> 5;
    float s0 = 0.f, s1 = 0.f;
#pragma unroll
    for (int i = 0; i < 16; ++i) {
        int c = i * 8 + ty;
        float2 x = *(const float2*)(fb + (size_t)c * NPTS + n0 + 2 * nslot);
        tile[2 * nslot][c] = x.x;
        tile[2 * nslot + 1][c] = x.y;
        s0 += x.x * x.x;
        s1 += x.y * x.y;
    }
    part[ty][2 * nslot] = s0;
    part[ty][2 * nslot + 1] = s1;
    __syncthreads();
    if (tid < 64) {  // one full wave: ballots are well-defined
        float s = 0.f;
#pragma unroll
        for (int t = 0; t < 8; ++t) s += part[t][tid];
        rn[tid] = 1.f / fmaxf(sqrtf(s), 1e-12f);
        int myl = labels[b * NPTS + n0 + tid] & 15;
        u64 mymask = 0ull;
#pragma unroll
        for (int L = 0; L < 16; ++L) {
            u64 bl = __ballot(myl == L);
            if (myl == L) mymask = bl;
        }
        int rank = __popcll(mymask & ((1ull << tid) - 1ull));
        int pos = baseg[(b * 64 + blk) * 16 + myl] + rank;
        lpos[tid] = pos;
        slab[b * NPTS + pos] = myl;
    }
    __syncthreads();
    u32* out = (u32*)vbf;
#pragma unroll
    for (int i = 0; i < 16; ++i) {
        int idx = tid + i * 256;
        int p = idx >> 6, k = idx & 63;
        float r = rn[p];
        float x0 = tile[p][2 * k] * r;
        float x1 = tile[p][2 * k + 1] * r;
        out[((size_t)b * NPTS + lpos[p]) * 64 + k] = (u32)f2bf(x0) | ((u32)f2bf(x1) << 16);
    }
}

// Kernel 2: similarity + exp2 + masked row partial sums on LABEL-SORTED points.
//   * sorted labels => ~88% of 16x16 tiles have a uniform mask (endpoint test),
//     epilogue drops from 5 VALU/elem to 2 (exp + one add into psame OR pneg).
//   * global_load_lds double-buffer, ONE barrier per 64-col tile; next tile's
//     loads issue after the barrier so the barrier's vmcnt(0) drain only waits
//     on loads that had a full compute phase to land (T3 minimal 2-phase).
//   * XOR swizzle kept by pre-swizzling the per-lane GLOBAL source address
//     (linear LDS dest + inverse-swz source + swz read).
// REGISTER BUDGET: launch_bounds (256,2) caps ARCH VGPRs at 128. Tripwire:
//   WRITE_SIZE in the 10s-100s of MB = scratch spill.
__global__ __launch_bounds__(256, 2) void sim_kernel(const u16* __restrict__ vbf,
                                                     const int* __restrict__ slab,
                                                     float2* __restrict__ rowacc) {
    int bid = blockIdx.x;
    int rt = bid >> 6;
    int combo = bid & 63;  // (cloud, cs): round-robin XCD dispatch spreads
    int b = combo >> 3;    // col-slabs across XCD L2s
    int cs = combo & 7;
    int row0 = rt * RPB;
    int c0 = cs * COLS_PER;
    int tid = threadIdx.x;
    int wave = tid >> 6, lane = tid & 63;
    int quad = lane >> 4, ln = lane & 15;

    const u16* vb = vbf + (size_t)b * NPTS * NC;
    const int* lab = slab + b * NPTS;

    int rbase[2];
    rbase[0] = row0 + wave * 32;
    rbase[1] = rbase[0] + 16;

    // A fragments, pre-scaled by log2(e): exp(dot) == exp2(scaled_dot)
    bf16x8 afrag[2][4];
#pragma unroll
    for (int s = 0; s < 2; ++s)
#pragma unroll
        for (int f = 0; f < 4; ++f) {
            bf16x8 v = *(const bf16x8*)(vb + (size_t)(rbase[s] + ln) * NC + f * 32 + quad * 8);
#pragma unroll
            for (int k = 0; k < 8; ++k) v[k] = (__bf16)((float)v[k] * 1.44269504f);
            afrag[s][f] = v;
        }

    int lrow[2][4];
#pragma unroll
    for (int s = 0; s < 2; ++s)
#pragma unroll
        for (int r = 0; r < 4; ++r) lrow[s][r] = lab[rbase[s] + quad * 4 + r];

    int row_uni[2];  // sorted => uniform iff endpoints match
#pragma unroll
    for (int s = 0; s < 2; ++s) row_uni[s] = (lab[rbase[s]] == lab[rbase[s] + 15]);

    int diagct[2], diagsub[2];
#pragma unroll
    for (int s = 0; s < 2; ++s) {
        diagct[s] = rbase[s] & ~63;  // fires only in the cs covering these cols
        diagsub[s] = (rbase[s] >> 4) & 3;
    }

    float psame[2][4] = {{0.f}}, pneg[2][4] = {{0.f}};

    __shared__ u16 cols[2][64 * 128];
    __shared__ int clabs[512];  // all this slab's col labels, staged once
    clabs[tid] = lab[c0 + tid];
    clabs[tid + 256] = lab[c0 + 256 + tid];

    const uint4* src = (const uint4*)(vb + (size_t)c0 * NC);
    // inverse-swizzled global offsets: LDS slot (rr,swcc) holds global chunk
    // cc = swcc ^ (rr&15); DMA writes linearly at base + lane*16.
    int g4[4];
#pragma unroll
    for (int i = 0; i < 4; ++i) {
        int idx16 = (wave * 4 + i) * 64 + lane;
        int rr = idx16 >> 4;
        int cc = (idx16 & 15) ^ (rr & 15);
        g4[i] = rr * 16 + cc;
    }

    int cur = 0;
    // prologue: stage tile 0
#pragma unroll
    for (int i = 0; i < 4; ++i)
        gload_lds16(src + g4[i], cols[0] + (wave * 4 + i) * 512);

    for (int t = 0; t < COLS_PER / 64; ++t) {
        __syncthreads();  // drains my stage(t) loads; everyone done with buf cur^1
        if (t < COLS_PER / 64 - 1) {
#pragma unroll
            for (int i = 0; i < 4; ++i)
                gload_lds16(src + (t + 1) * 1024 + g4[i], cols[cur ^ 1] + (wave * 4 + i) * 512);
        }
        int ct = c0 + t * 64;

#pragma unroll
        for (int sub = 0; sub < 4; ++sub) {
            const u16* rowb = cols[cur] + (sub * 16 + ln) * 128;
            bf16x8 bfrag[4];
#pragma unroll
            for (int f = 0; f < 4; ++f)
                bfrag[f] = *(const bf16x8*)(rowb + (((4 * f + quad) ^ ln) * 8));
            int lc = clabs[t * 64 + sub * 16 + ln];
            int clo = __shfl(lc, 0), chi = __shfl(lc, 15);
#pragma unroll
            for (int s = 0; s < 2; ++s) {
                f32x4 d = {0.f, 0.f, 0.f, 0.f};
#pragma unroll
                for (int f = 0; f < 4; ++f)
                    d = __builtin_amdgcn_mfma_f32_16x16x32_bf16(afrag[s][f], bfrag[f], d, 0, 0, 0);
                if (ct == diagct[s] && sub == diagsub[s]) {  // wave-uniform, rare
#pragma unroll
                    for (int r = 0; r < 4; ++r) {
                        float e = fast_exp2(d[r]);
                        if (ln == quad * 4 + r) e = 0.f;  // zero the diagonal
                        bool m = (lc == lrow[s][r]);
                        psame[s][r] += m ? e : 0.f;
                        pneg[s][r] += m ? 0.f : e;
                    }
                } else if (row_uni[s] && clo == chi) {  // uniform tile: 2 ops/elem
                    if (clo == lrow[s][0]) {
#pragma unroll
                        for (int r = 0; r < 4; ++r) psame[s][r] += fast_exp2(d[r]);
                    } else {
#pragma unroll
                        for (int r = 0; r < 4; ++r) pneg[s][r] += fast_exp2(d[r]);
                    }
                } else {  // boundary tile (~12%)
#pragma unroll
                    for (int r = 0; r < 4; ++r) {
                        float e = fast_exp2(d[r]);
                        bool m = (lc == lrow[s][r]);
                        psame[s][r] += m ? e : 0.f;
                        pneg[s][r] += m ? 0.f : e;
                    }
                }
            }
        }
        cur ^= 1;
    }

#pragma unroll
    for (int off = 1; off < 16; off <<= 1)
#pragma unroll
        for (int s = 0; s < 2; ++s)
#pragma unroll
            for (int r = 0; r < 4; ++r) {
                psame[s][r] += __shfl_xor(psame[s][r], off);
                pneg[s][r] += __shfl_xor(pneg[s][r], off);
            }
    if (ln == 0) {
#pragma unroll
        for (int s = 0; s < 2; ++s)
#pragma unroll
            for (int r = 0; r < 4; ++r)
                rowacc[((size_t)cs * NB + b) * NPTS + rbase[s] + quad * 4 + r] =
                    make_float2(psame[s][r], pneg[s][r]);
    }
}

// Kernel 3: per-row finalize + mean; last block (ticket) writes d_out.
// Rows are in sorted order; mean is permutation-invariant, labels from slab.
__global__ __launch_bounds__(256) void loss_kernel(const float2* __restrict__ rowacc,
                                                   const int* __restrict__ slab,
                                                   const int* __restrict__ counts,
                                                   float* __restrict__ acc,
                                                   u32* __restrict__ ticket,
                                                   float* __restrict__ out) {
    int idx = blockIdx.x * 256 + threadIdx.x;  // 0..B*NPTS-1
    int b = idx >> 12;
    float ps = 0.f, pn = 0.f;
#pragma unroll
    for (int cs = 0; cs < CSPLIT; ++cs) {
        float2 v = rowacc[(size_t)cs * NB * NPTS + idx];
        ps += v.x;
        pn += v.y;
    }
    int lb = slab[idx] & 15;
    int cnt = counts[b * 16 + lb];
    float p = ps / (float)cnt;
    float n = pn / (float)(NPTS - cnt);
    float loss = -__logf(p / (p + n));
#pragma unroll
    for (int off = 1; off < 64; off <<= 1) loss += __shfl_xor(loss, off);
    __shared__ float w[4];
    if ((threadIdx.x & 63) == 0) w[threadIdx.x >> 6] = loss;
    __syncthreads();
    if (threadIdx.x == 0) {
        atomicAdd(acc, w[0] + w[1] + w[2] + w[3]);
        __threadfence();
        u32 t = atomicAdd(ticket, 1u);
        if (t == gridDim.x - 1) {            // all blocks' adds visible
            float v = atomicAdd(acc, 0.f);   // coherent read of final sum
            out[0] = v * (1.f / (float)(NB * NPTS));
        }
    }
}

extern "C" void kernel_launch(void* const* d_in, const int* in_sizes, int n_in,
                              void* d_out, int out_size, void* d_ws, size_t ws_size,
                              hipStream_t stream) {
    const float* feat = (const float*)d_in[0];
    const int* labels = (const int*)d_in[1];
    float* out = (float*)d_out;

    float* acc = (float*)d_ws;                        // @0, 4 B
    u32* ticket = (u32*)((char*)d_ws + 4);            // @4, 4 B
    int* counts = (int*)((char*)d_ws + 256);          // 8*16*4 = 512 B
    int* baseg = (int*)((char*)d_ws + 1024);          // 8*64*16*4 = 32 KB
    int* slab = (int*)((char*)d_ws + 36864);          // 8*4096*4 = 128 KB
    float2* rowacc = (float2*)((char*)d_ws + 172032); // 8*8*4096*8 = 2 MB
    u16* vbf = (u16*)((char*)d_ws + 172032 + (size_t)CSPLIT * NB * NPTS * 8);  // 8 MB

    hist_kernel<<<dim3(NB), 256, 0, stream>>>(labels, counts, baseg, (u32*)d_ws);
    norm_kernel<<<dim3(64, NB), 256, 0, stream>>>(feat, labels, baseg, vbf, slab);
    sim_kernel<<<dim3(32 * 64), 256, 0, stream>>>(vbf, slab, rowacc);
    loss_kernel<<<dim3(NB * NPTS / 256), 256, 0, stream>>>(rowacc, slab, counts, acc, ticket, out);
}